// Round 2
// baseline (303.792 us; speedup 1.0000x reference)
//
#include <hip/hip_runtime.h>

#define NN   16
#define CC   3
#define FOUT 64
#define HH   256
#define WW   256
#define KK   3
#define HO   254
#define WO   254
#define FSPLIT 4
#define FPW  (FOUT / FSPLIT)   // 16 filters per wave

// 16B vector with 8B alignment guarantee: output rows are 1016B apart, so the
// 16B stores are only 8B-aligned. AMDGPU emits a single global_store_dwordx4
// for align>=4.
typedef float f32x4_a8 __attribute__((ext_vector_type(4), aligned(8)));

__global__ __launch_bounds__(256) void conv2dcq_kernel(
    const float* __restrict__ x,       // (N, C, H, W)
    const float* __restrict__ weight,  // (F, C, K, K)
    const float* __restrict__ bias,    // (F,)
    float* __restrict__ out)           // (N, F, HO, WO)
{
    // Weights (channel CC-1) + bias, padded to 12 floats/filter:
    // [0..8] = w, [9] = bias. 48B rows, 16B-aligned -> ds_read_b128 x2 + b64.
    __shared__ __align__(16) float w_lds[FOUT][12];

    const int tid = threadIdx.x;
    for (int idx = tid; idx < FOUT * 10; idx += 256) {
        const int f = idx / 10, k = idx - f * 10;
        w_lds[f][k] = (k < 9)
            ? weight[f * (CC * KK * KK) + (CC - 1) * (KK * KK) + k]
            : bias[f];
    }
    __syncthreads();

    const int lane = tid & 63;
    const int wave = tid >> 6;

    // Block = one output row (n, i). Wave = one quarter of the filters.
    // 4064 blocks -> ~16 blocks/CU -> 32 resident waves/CU (full occupancy),
    // 4x the store-issuing waves of the previous version.
    const int row = blockIdx.x;                // 0 .. NN*HO-1
    const int n   = row / HO;
    const int i   = row - n * HO;
    const int fbase = wave * FPW;              // 0, 16, 32, 48

    // Lane l -> output cols 4l..4l+3. Lane 63 -> cols 250..253, overlapping
    // lane 62's cols 250..251 with bit-identical values -> benign double-store,
    // no tail branch; wave store = ONE contiguous 1016B burst per filter.
    const int j = (lane < 63) ? 4 * lane : 250;

    // Input: channel 0, rows i..i+2, cols j..j+5.
    const float* xp = x + (size_t)n * (CC * HH * WW) + (size_t)i * WW + j;
    float in[3][6];
    #pragma unroll
    for (int r = 0; r < 3; ++r) {
        const f32x4_a8 a = *(const f32x4_a8*)(xp + r * WW);      // 16B chunk
        const float2   c = *(const float2*)(xp + r * WW + 4);    // 8B chunk
        in[r][0] = a.x; in[r][1] = a.y; in[r][2] = a.z; in[r][3] = a.w;
        in[r][4] = c.x; in[r][5] = c.y;
    }

    float* op = out + ((size_t)n * FOUT + fbase) * (HO * WO) + (size_t)i * WO + j;

    #pragma unroll 4
    for (int f = fbase; f < fbase + FPW; ++f) {
        const f32x4_a8 w0 = *(const f32x4_a8*)(&w_lds[f][0]);    // ds_read_b128
        const f32x4_a8 w1 = *(const f32x4_a8*)(&w_lds[f][4]);    // ds_read_b128
        const float2   wb = *(const float2*)(&w_lds[f][8]);      // ds_read_b64: w8, bias

        const float wv[9] = { w0.x, w0.y, w0.z, w0.w,
                              w1.x, w1.y, w1.z, w1.w, wb.x };
        float acc[4] = { wb.y, wb.y, wb.y, wb.y };
        #pragma unroll
        for (int a = 0; a < 3; ++a) {
            #pragma unroll
            for (int q = 0; q < 3; ++q) {
                const float wq = wv[a * 3 + q];
                #pragma unroll
                for (int c = 0; c < 4; ++c)
                    acc[c] = fmaf(wq, in[a][q + c], acc[c]);
            }
        }

        f32x4_a8 v; v.x = acc[0]; v.y = acc[1]; v.z = acc[2]; v.w = acc[3];
        // Non-temporal: stream past L2 write-allocate (output is write-once,
        // never re-read by this kernel).
        __builtin_nontemporal_store(v, (f32x4_a8*)op);
        op += HO * WO;
    }
}

extern "C" void kernel_launch(void* const* d_in, const int* in_sizes, int n_in,
                              void* d_out, int out_size, void* d_ws, size_t ws_size,
                              hipStream_t stream) {
    const float* x      = (const float*)d_in[0];
    const float* weight = (const float*)d_in[1];
    const float* bias   = (const float*)d_in[2];
    float* out          = (float*)d_out;

    const int blocks = NN * HO;                // 4064 blocks, one output row each
    conv2dcq_kernel<<<blocks, 256, 0, stream>>>(x, weight, bias, out);
}

// Round 3
// 268.028 us; speedup vs baseline: 1.1334x; 1.1334x over previous
//
#include <hip/hip_runtime.h>

#define NN   16
#define CC   3
#define FOUT 64
#define HH   256
#define WW   256
#define KK   3
#define HO   254
#define WO   254

// Input 16B chunks are only 8B-aligned (row phase); stores below are真16B-aligned.
typedef float f32x4_a8  __attribute__((ext_vector_type(4), aligned(8)));
typedef float f32x4_a16 __attribute__((ext_vector_type(4), aligned(16)));

__global__ __launch_bounds__(256) void conv2dcq_kernel(
    const float* __restrict__ x,       // (N, C, H, W)
    const float* __restrict__ weight,  // (F, C, K, K)
    const float* __restrict__ bias,    // (F,)
    float* __restrict__ out)           // (N, F, HO, WO)
{
    // Weights (channel CC-1) + bias, padded to 12 floats/filter:
    // [0..8] = w, [9] = bias. 48B rows, 16B-aligned -> ds_read_b128 x2 + b64.
    __shared__ __align__(16) float w_lds[FOUT][12];

    const int tid = threadIdx.x;
    for (int idx = tid; idx < FOUT * 10; idx += 256) {
        const int f = idx / 10, k = idx - f * 10;
        w_lds[f][k] = (k < 9)
            ? weight[f * (CC * KK * KK) + (CC - 1) * (KK * KK) + k]
            : bias[f];
    }
    __syncthreads();

    const int lane = tid & 63;
    const int wave = tid >> 6;

    // XCD-chunk swizzle (bijective: 1016 = 8 * 127): consecutive rows land on
    // the SAME XCD so row-boundary cache lines (1016 % 64 = 56) coalesce in
    // one L2 instead of partial-line evictions from two non-coherent L2s.
    const int bid   = (int)blockIdx.x;
    const int swz   = (bid & 7) * 127 + (bid >> 3);
    const int gwave = swz * 4 + wave;          // one wave per output row
    const int n  = gwave / HO;
    const int i  = gwave - n * HO;             // output row

    // Row byte base ≡ 8*(i&1) (mod 16)  [plane stride 258064 ≡ 0, row 1016 ≡ 8].
    // Phase-shift lane->col map on odd rows so EVERY x4 store is 16B-aligned:
    //   lanes 0..62: cols [4l+2p, 4l+2p+3], store addr = rowbase + 8p + 16l ≡ 0 (16)
    //   lane 63:     p=0 -> computes cols 250..253, stores cols 252,253 (tail 8B)
    //                p=1 -> computes cols 0..3,     stores cols 0,1     (head 8B)
    const int phase = i & 1;
    const int j = (lane < 63) ? (4 * lane + 2 * phase) : (phase ? 0 : 250);

    // Input: channel 0, rows i..i+2, cols j..j+5 (j even -> 8B-aligned loads).
    const float* xp = x + (size_t)n * (CC * HH * WW) + (size_t)i * WW + j;
    float in[3][6];
    #pragma unroll
    for (int r = 0; r < 3; ++r) {
        const f32x4_a8 a = *(const f32x4_a8*)(xp + r * WW);
        const float2   c = *(const float2*)(xp + r * WW + 4);
        in[r][0] = a.x; in[r][1] = a.y; in[r][2] = a.z; in[r][3] = a.w;
        in[r][4] = c.x; in[r][5] = c.y;
    }

    float* op = out + (size_t)n * (FOUT * HO * WO) + (size_t)i * WO + j;
    const bool full = (lane < 63);
    const int  tailoff = phase ? 0 : 2;        // lane 63: float2 at acc[0:2) or acc[2:4)

    #pragma unroll 4
    for (int f = 0; f < FOUT; ++f) {
        const f32x4_a16 w0 = *(const f32x4_a16*)(&w_lds[f][0]);  // ds_read_b128
        const f32x4_a16 w1 = *(const f32x4_a16*)(&w_lds[f][4]);  // ds_read_b128
        const float2    wb = *(const float2*)(&w_lds[f][8]);     // ds_read_b64: w8, bias

        const float wv[9] = { w0.x, w0.y, w0.z, w0.w,
                              w1.x, w1.y, w1.z, w1.w, wb.x };
        float acc[4] = { wb.y, wb.y, wb.y, wb.y };
        #pragma unroll
        for (int a = 0; a < 3; ++a) {
            #pragma unroll
            for (int q = 0; q < 3; ++q) {
                const float wq = wv[a * 3 + q];
                #pragma unroll
                for (int c = 0; c < 4; ++c)
                    acc[c] = fmaf(wq, in[a][q + c], acc[c]);
            }
        }

        if (full) {
            f32x4_a16 v; v.x = acc[0]; v.y = acc[1]; v.z = acc[2]; v.w = acc[3];
            *(f32x4_a16*)op = v;               // 16B-aligned dwordx4, no split
        } else {
            *(float2*)(op + tailoff) = make_float2(acc[tailoff], acc[tailoff + 1]);
        }
        op += HO * WO;
    }
}

extern "C" void kernel_launch(void* const* d_in, const int* in_sizes, int n_in,
                              void* d_out, int out_size, void* d_ws, size_t ws_size,
                              hipStream_t stream) {
    const float* x      = (const float*)d_in[0];
    const float* weight = (const float*)d_in[1];
    const float* bias   = (const float*)d_in[2];
    float* out          = (float*)d_out;

    const int total_waves = NN * HO;           // 4064 rows, one wave each
    const int blocks = total_waves / 4;        // 1016 blocks = 8 XCD chunks of 127
    conv2dcq_kernel<<<blocks, 256, 0, stream>>>(x, weight, bias, out);
}